// Round 2
// baseline (545.683 us; speedup 1.0000x reference)
//
#include <hip/hip_runtime.h>
#include <math.h>

#define D 128
#define H 64
#define W 100
#define R 20
#define NB 256
#define NDOC_UI (NB * R)            // 5120
#define NDOC    (2 * NDOC_UI + NB)  // 10496
#define VOCAB 50000
#define GRID 512                    // 2 blocks/CU, co-resident by launch_bounds
#define TPB  512
#define DOCS_PER_BLK 82             // NDOC / 128 rb-classes

// e^(2x) identity tanh: exact saturation at +-1 via inf/0 in rcp.
__device__ __forceinline__ float fast_tanh(float x) {
    float u = __expf(2.0f * x);
    return 1.0f - 2.0f * __builtin_amdgcn_rcpf(1.0f + u);
}
__device__ __forceinline__ float fast_exp_tanh(float x) {
    return __expf(fast_tanh(x));
}

// fp32 -> bf16 round-to-nearest-even
__device__ __forceinline__ unsigned short f2bf(float f) {
    unsigned int b = __float_as_uint(f);
    b += 0x7fffu + ((b >> 16) & 1u);
    return (unsigned short)(b >> 16);
}

// Monotonic grid-barrier counters. Device globals: zero at module load,
// NOT in ws (harness poisons ws). Each launch adds exactly GRID to each
// counter, so target = (old & ~(GRID-1)) + GRID needs no reset/memset.
__device__ unsigned g_sync[3];

// Cache-friendly device barrier:
//  - arrive: fetch_add RELEASE (ONE L2 writeback per block)
//  - spin:   RELAXED loads (sc0/sc1 bypass, see remote updates, NO invalidate)
//  - exit:   ONE ACQUIRE load (single L2 invalidate per block)
// R1's ACQUIRE-in-spin-loop invalidated the XCD L2 every ~500cy and cost ~100us.
__device__ __forceinline__ void grid_barrier(int k) {
    __syncthreads();
    if (threadIdx.x == 0) {
        unsigned o = __hip_atomic_fetch_add(&g_sync[k], 1u,
                        __ATOMIC_RELEASE, __HIP_MEMORY_SCOPE_AGENT);
        unsigned target = (o & ~(unsigned)(GRID - 1)) + GRID;
        while ((int)(__hip_atomic_load(&g_sync[k], __ATOMIC_RELAXED,
                        __HIP_MEMORY_SCOPE_AGENT) - target) < 0)
            __builtin_amdgcn_s_sleep(2);
        (void)__hip_atomic_load(&g_sync[k], __ATOMIC_ACQUIRE,
                                __HIP_MEMORY_SCOPE_AGENT);
    }
    __syncthreads();
}

// =============================================================================
// Fused persistent kernel: vocab_prep -> doc_embed -> pv -> attn.
// 512 blocks x 512 threads, 2 blocks/CU (launch_bounds-guaranteed capacity).
// =============================================================================
__global__ __launch_bounds__(TPB, 4) void fused_kernel(
    const int* __restrict__ user_w, const int* __restrict__ item_w,
    const int* __restrict__ query_w,
    const float* __restrict__ emb, const float* __restrict__ w_self,
    const float* __restrict__ b_self,
    const float* __restrict__ Wq, const float* __restrict__ bq,
    const float* __restrict__ w_red, const float* __restrict__ pf,
    float* __restrict__ user_emb, float* __restrict__ item_emb,
    float* __restrict__ q_emb, float* __restrict__ pv,
    float* __restrict__ evocab, ushort* __restrict__ emb_bf,
    float* __restrict__ out)
{
    __shared__ __align__(16) float smem[128 * 68];   // 34.8 KB (Wq tile / attn)
    const int tid    = threadIdx.x;
    const int bx     = blockIdx.x;
    const int lane32 = tid & 31;

    // ---- Phase 3 prologue hoisted: stage this block's Wq column tile now so
    //      its HBM reads overlap phase 1's streaming (independent of all phases).
    {
        const int dd   = bx >> 2;             // 0..127
        int rrow = tid >> 4;                  // 0..31
        int f4   = tid & 15;
        #pragma unroll
        for (int pass = 0; pass < 4; ++pass) {
            int k = pass * 32 + rrow;
            float4 vw = ((const float4*)Wq)[k * 2048 + dd * 16 + f4];
            *(float4*)&smem[k * 68 + f4 * 4] = vw;
        }
        // visibility to other waves covered by grid_barrier's __syncthreads
    }

    // ---------------- Phase 1: vocab prep (grid-stride, 16 rows/block/iter) --
    {
        const int grp16 = tid >> 5;                  // 0..15
        float4 ws4 = ((const float4*)w_self)[lane32];
        float  bs  = b_self[0];
        for (int row = bx * 16 + grp16; row < VOCAB; row += GRID * 16) {
            float4 v = ((const float4*)emb)[row * 32 + lane32];
            float p = v.x * ws4.x + v.y * ws4.y + v.z * ws4.z + v.w * ws4.w;
            p += __shfl_xor(p, 16, 64);
            p += __shfl_xor(p, 8, 64);
            p += __shfl_xor(p, 4, 64);
            p += __shfl_xor(p, 2, 64);
            p += __shfl_xor(p, 1, 64);
            float e = __expf(tanhf(p + bs));         // precise tanh: 50K evals
            if (lane32 == 0) evocab[row] = e;
            ushort4 u;
            u.x = f2bf(v.x * e); u.y = f2bf(v.y * e);
            u.z = f2bf(v.z * e); u.w = f2bf(v.w * e);
            int q = lane32 >> 3;                     // d-quarter of this lane
            ushort4* dst = (ushort4*)(emb_bf + (size_t)q * VOCAB * 32);
            dst[row * 8 + (lane32 & 7)] = u;
        }
    }
    grid_barrier(0);

    // ---------------- Phase 2: doc embed (XCD-pinned quarter tables) ---------
    // bx%8 ~ XCD; quar=(bx&7)>>1 pins one 3.2MB quarter table per XCD L2.
    // 128 rb-classes x 82 docs, 16 lane-groups/block -> 6 iterations.
    {
        const int quar = (bx & 7) >> 1;
        const int rb   = ((bx >> 3) << 1) | (bx & 1);   // 0..127 within class
        const int g    = tid >> 5;                      // 0..15
        const int permbase = (tid & 32) << 2;
        const int wsub = lane32 >> 2;
        const int sext = lane32 & 3;
        const uint4* eq4 = (const uint4*)(emb_bf + (size_t)quar * VOCAB * 32);

        for (int it = 0; it < 6; ++it) {
            int local = it * 16 + g;
            if (local >= DOCS_PER_BLK) break;
            int doc = rb * DOCS_PER_BLK + local;

            const int* wp; float* outp;
            if (doc < NDOC_UI)        { wp = user_w + doc * W;               outp = user_emb + doc * D; }
            else if (doc < 2*NDOC_UI) { int t2 = doc - NDOC_UI;   wp = item_w  + t2 * W; outp = item_emb + t2 * D; }
            else                      { int t2 = doc - 2*NDOC_UI; wp = query_w + t2 * W; outp = q_emb    + t2 * D; }

            int wreg[4];
            #pragma unroll
            for (int k = 0; k < 4; ++k) {
                int idx = k * 32 + lane32;
                wreg[k] = wp[idx > W - 1 ? W - 1 : idx];
            }

            float ep = 0.f;
            #pragma unroll
            for (int k = 0; k < 4; ++k) {
                float e = evocab[wreg[k]];
                if (k < 3 || lane32 < 4) ep += e;
            }
            ep += __shfl_xor(ep, 16, 64);
            ep += __shfl_xor(ep, 8, 64);
            ep += __shfl_xor(ep, 4, 64);
            ep += __shfl_xor(ep, 2, 64);
            ep += __shfl_xor(ep, 1, 64);
            float inv = 1.f / ep;

            float acc[8];
            #pragma unroll
            for (int j = 0; j < 8; ++j) acc[j] = 0.f;

            #pragma unroll
            for (int c = 0; c < 2; ++c) {
                const int n  = (c == 0) ? 7 : 6;
                const int s0 = (c == 0) ? 0 : 7;
                int wid[7]; uint4 v[7];
                for (int j = 0; j < n; ++j) {
                    int s = s0 + j;
                    wid[j] = __builtin_amdgcn_ds_bpermute(
                        permbase | ((((8 * s) & 31) + wsub) << 2), wreg[s >> 2]);
                }
                for (int j = 0; j < n; ++j)
                    v[j] = eq4[(size_t)(unsigned)wid[j] * 4 + sext];
                for (int j = 0; j < n; ++j) {
                    if (s0 + j == 12 && wsub >= 4) break;   // tail mask
                    uint4 x = v[j];
                    acc[0] += __uint_as_float(x.x << 16);
                    acc[1] += __uint_as_float(x.x & 0xffff0000u);
                    acc[2] += __uint_as_float(x.y << 16);
                    acc[3] += __uint_as_float(x.y & 0xffff0000u);
                    acc[4] += __uint_as_float(x.z << 16);
                    acc[5] += __uint_as_float(x.z & 0xffff0000u);
                    acc[6] += __uint_as_float(x.w << 16);
                    acc[7] += __uint_as_float(x.w & 0xffff0000u);
                }
            }

            #pragma unroll
            for (int j = 0; j < 8; ++j) {
                acc[j] += __shfl_xor(acc[j], 4, 64);
                acc[j] += __shfl_xor(acc[j], 8, 64);
                acc[j] += __shfl_xor(acc[j], 16, 64);
            }

            if (wsub == 0) {
                float* o = outp + quar * 32 + sext * 8;
                *(float4*)o       = make_float4(acc[0]*inv, acc[1]*inv, acc[2]*inv, acc[3]*inv);
                *(float4*)(o + 4) = make_float4(acc[4]*inv, acc[5]*inv, acc[6]*inv, acc[7]*inv);
            }
        }
    }
    grid_barrier(1);

    // ---------------- Phase 3: pv[b,d] = sum_h tanh(q@Wq+bq)*w_red -----------
    // One block = (dd, m-quarter): 64 rows x 64 h; Wq tile already in LDS.
    {
        const int dd  = bx >> 2;
        const int m0g = (bx & 3) * 64;

        int nthr = tid & 15;
        int mthr = tid >> 4;                  // 0..31
        int n0 = nthr * 4;
        const float4* q4 = (const float4*)q_emb;
        int mbase = m0g + mthr * 2;

        float acc[2][4];
        #pragma unroll
        for (int i = 0; i < 2; ++i)
            #pragma unroll
            for (int j = 0; j < 4; ++j) acc[i][j] = 0.f;

        float4 qa[2], qb[2];
        #pragma unroll
        for (int i = 0; i < 2; ++i) qa[i] = q4[(mbase + i) * 32];

        for (int k4 = 0; k4 < 32; ++k4) {
            if (k4 < 31) {
                #pragma unroll
                for (int i = 0; i < 2; ++i) qb[i] = q4[(mbase + i) * 32 + k4 + 1];
            }
            #pragma unroll
            for (int kk = 0; kk < 4; ++kk) {
                float4 wv = *(const float4*)&smem[(k4 * 4 + kk) * 68 + n0];
                #pragma unroll
                for (int i = 0; i < 2; ++i) {
                    float a = (kk == 0) ? qa[i].x : (kk == 1) ? qa[i].y
                            : (kk == 2) ? qa[i].z : qa[i].w;
                    acc[i][0] += a * wv.x;
                    acc[i][1] += a * wv.y;
                    acc[i][2] += a * wv.z;
                    acc[i][3] += a * wv.w;
                }
            }
            #pragma unroll
            for (int i = 0; i < 2; ++i) qa[i] = qb[i];
        }

        float4 bqv = ((const float4*)bq)[dd * 16 + nthr];
        float4 wrv = ((const float4*)w_red)[nthr];

        #pragma unroll
        for (int i = 0; i < 2; ++i) {
            float s = fast_tanh(acc[i][0] + bqv.x) * wrv.x
                    + fast_tanh(acc[i][1] + bqv.y) * wrv.y
                    + fast_tanh(acc[i][2] + bqv.z) * wrv.z
                    + fast_tanh(acc[i][3] + bqv.w) * wrv.w;
            s += __shfl_xor(s, 1, 64);
            s += __shfl_xor(s, 2, 64);
            s += __shfl_xor(s, 4, 64);
            s += __shfl_xor(s, 8, 64);
            if (nthr == 0) pv[(mbase + i) * 128 + dd] = s;
        }
    }
    grid_barrier(2);

    // ---------------- Phase 4: review attention + output ---------------------
    // One block per (b, set): b = bx>>1, set = bx&1.
    {
        const int b   = bx >> 1;
        const int set = bx & 1;
        const float* revg = (set == 0 ? user_emb : item_emb) + b * R * D;
        float* srev = smem;                   // R*129 = 2580 floats
        float* pvl  = smem + R * 129;         // 128
        float* ssc  = pvl + D;                // 20

        for (int idx = tid; idx < R * D; idx += TPB)
            srev[(idx >> 7) * 129 + (idx & 127)] = revg[idx];
        if (tid < D) pvl[tid] = pv[b * D + tid];
        __syncthreads();

        if (tid < R) {
            float s = 0.f;
            const float* row = &srev[tid * 129];
            #pragma unroll 16
            for (int k = 0; k < D; ++k) s += row[k] * pvl[k];
            ssc[tid] = s;
        }
        __syncthreads();

        float m = -1e30f;
        for (int r = 0; r < R; ++r) m = fmaxf(m, ssc[r]);
        float sum = 0.f;
        for (int r = 0; r < R; ++r) sum += __expf(ssc[r] - m);
        float inv = 1.f / sum;

        if (tid < D) {
            float acc2 = 0.f;
            for (int r = 0; r < R; ++r)
                acc2 += __expf(ssc[r] - m) * inv * srev[r * 129 + tid];
            if (set == 0) {
                acc2 += pf[0] * q_emb[b * D + tid];
                out[b * D + tid] = acc2;
            } else {
                out[NB * D + b * D + tid] = acc2;
            }
        }
    }
}

// =============================================================================
// Fallback (small ws): R4-proven fp32 gather doc embed + separate pv/attn.
// =============================================================================
__global__ __launch_bounds__(256, 7) void doc_embed_fp32_kernel(
    const int* __restrict__ user_w, const int* __restrict__ item_w,
    const int* __restrict__ query_w,
    const float* __restrict__ emb, const float* __restrict__ w_self,
    const float* __restrict__ b_self,
    float* __restrict__ user_emb, float* __restrict__ item_emb,
    float* __restrict__ q_emb)
{
    int tid    = threadIdx.x;
    int lane32 = tid & 31;
    int grp    = tid >> 5;
    int doc    = blockIdx.x * 8 + grp;

    const int* wp; float* outp;
    if (doc < NDOC_UI)        { wp = user_w + doc * W;               outp = user_emb + doc * D; }
    else if (doc < 2*NDOC_UI) { int t = doc - NDOC_UI;   wp = item_w  + t * W; outp = item_emb + t * D; }
    else                      { int t = doc - 2*NDOC_UI; wp = query_w + t * W; outp = q_emb    + t * D; }

    int wreg[4];
    #pragma unroll
    for (int k = 0; k < 4; ++k) {
        int idx = k * 32 + lane32;
        wreg[k] = wp[idx > W - 1 ? W - 1 : idx];
    }

    float4 ws4 = ((const float4*)w_self)[lane32];
    float  bs  = b_self[0];
    const float4* emb4 = (const float4*)emb;
    int permbase = (tid & 32) * 4;

    float4 acc  = make_float4(0.f, 0.f, 0.f, 0.f);
    float  esum = 0.f;

    #pragma unroll
    for (int c = 0; c < 10; ++c) {
        int word[10];
        #pragma unroll
        for (int j = 0; j < 10; ++j) {
            int w = c * 10 + j;
            word[j] = __builtin_amdgcn_ds_bpermute(permbase | ((w & 31) * 4),
                                                   wreg[w >> 5]);
        }
        float4 v[10];
        #pragma unroll
        for (int j = 0; j < 10; ++j)
            v[j] = emb4[(size_t)word[j] * 32 + lane32];

        #pragma unroll
        for (int j = 0; j < 10; ++j) {
            float p = v[j].x * ws4.x + v[j].y * ws4.y + v[j].z * ws4.z + v[j].w * ws4.w;
            p += __shfl_xor(p, 16, 64);
            p += __shfl_xor(p, 8, 64);
            p += __shfl_xor(p, 4, 64);
            p += __shfl_xor(p, 2, 64);
            p += __shfl_xor(p, 1, 64);
            float e = fast_exp_tanh(p + bs);
            esum += e;
            acc.x += e * v[j].x;
            acc.y += e * v[j].y;
            acc.z += e * v[j].z;
            acc.w += e * v[j].w;
        }
    }

    float inv = 1.0f / esum;
    acc.x *= inv; acc.y *= inv; acc.z *= inv; acc.w *= inv;
    ((float4*)outp)[lane32] = acc;
}

__global__ __launch_bounds__(256) void pv_kernel(
    const float* __restrict__ q_emb, const float* __restrict__ Wq,
    const float* __restrict__ bq, const float* __restrict__ w_red,
    float* __restrict__ pv)
{
    __shared__ __align__(16) float Wb[128 * 68];

    int dd  = blockIdx.x;
    int m0g = blockIdx.y * 128;
    int tid = threadIdx.x;

    {
        int rrow = tid >> 4;
        int f4   = tid & 15;
        #pragma unroll
        for (int pass = 0; pass < 8; ++pass) {
            int k = pass * 16 + rrow;
            float4 vw = ((const float4*)Wq)[k * 2048 + dd * 16 + f4];
            *(float4*)&Wb[k * 68 + f4 * 4] = vw;
        }
    }
    __syncthreads();

    int nthr = tid & 15;
    int mthr = tid >> 4;
    int n0 = nthr * 4;
    const float4* q4 = (const float4*)q_emb;
    int mbase = (m0g + mthr * 8) * 32;

    float acc[8][4];
    #pragma unroll
    for (int i = 0; i < 8; ++i)
        #pragma unroll
        for (int j = 0; j < 4; ++j) acc[i][j] = 0.f;

    float4 qa[8], qb[8];
    #pragma unroll
    for (int i = 0; i < 8; ++i) qa[i] = q4[mbase + i * 32];

    for (int k4 = 0; k4 < 32; ++k4) {
        if (k4 < 31) {
            #pragma unroll
            for (int i = 0; i < 8; ++i) qb[i] = q4[mbase + i * 32 + k4 + 1];
        }
        #pragma unroll
        for (int kk = 0; kk < 4; ++kk) {
            float4 wv = *(const float4*)&Wb[(k4 * 4 + kk) * 68 + n0];
            #pragma unroll
            for (int i = 0; i < 8; ++i) {
                float a = (kk == 0) ? qa[i].x : (kk == 1) ? qa[i].y
                        : (kk == 2) ? qa[i].z : qa[i].w;
                acc[i][0] += a * wv.x;
                acc[i][1] += a * wv.y;
                acc[i][2] += a * wv.z;
                acc[i][3] += a * wv.w;
            }
        }
        #pragma unroll
        for (int i = 0; i < 8; ++i) qa[i] = qb[i];
    }

    float4 bqv = ((const float4*)bq)[dd * 16 + nthr];
    float4 wrv = ((const float4*)w_red)[nthr];

    #pragma unroll
    for (int i = 0; i < 8; ++i) {
        float s = fast_tanh(acc[i][0] + bqv.x) * wrv.x
                + fast_tanh(acc[i][1] + bqv.y) * wrv.y
                + fast_tanh(acc[i][2] + bqv.z) * wrv.z
                + fast_tanh(acc[i][3] + bqv.w) * wrv.w;
        s += __shfl_xor(s, 1, 64);
        s += __shfl_xor(s, 2, 64);
        s += __shfl_xor(s, 4, 64);
        s += __shfl_xor(s, 8, 64);
        if (nthr == 0) pv[(m0g + mthr * 8 + i) * 128 + dd] = s;
    }
}

__global__ __launch_bounds__(256) void attn_kernel(
    const float* __restrict__ user_emb, const float* __restrict__ item_emb,
    const float* __restrict__ q_emb, const float* __restrict__ pv,
    const float* __restrict__ pf, float* __restrict__ out)
{
    __shared__ float rev[R * 129];
    __shared__ float pvl[D];
    __shared__ float sc[R];

    int b   = blockIdx.x;
    int set = blockIdx.y;
    const float* revg = (set == 0 ? user_emb : item_emb) + b * R * D;
    int tid = threadIdx.x;

    for (int idx = tid; idx < R * D; idx += 256)
        rev[(idx >> 7) * 129 + (idx & 127)] = revg[idx];
    if (tid < D) pvl[tid] = pv[b * D + tid];
    __syncthreads();

    if (tid < R) {
        float s = 0.f;
        const float* row = &rev[tid * 129];
        #pragma unroll 16
        for (int k = 0; k < D; ++k) s += row[k] * pvl[k];
        sc[tid] = s;
    }
    __syncthreads();

    float m = -1e30f;
    for (int r = 0; r < R; ++r) m = fmaxf(m, sc[r]);
    float sum = 0.f;
    for (int r = 0; r < R; ++r) sum += __expf(sc[r] - m);
    float inv = 1.f / sum;

    if (tid < D) {
        float acc = 0.f;
        for (int r = 0; r < R; ++r)
            acc += __expf(sc[r] - m) * inv * rev[r * 129 + tid];
        if (set == 0) {
            acc += pf[0] * q_emb[b * D + tid];
            out[b * D + tid] = acc;
        } else {
            out[NB * D + b * D + tid] = acc;
        }
    }
}

extern "C" void kernel_launch(void* const* d_in, const int* in_sizes, int n_in,
                              void* d_out, int out_size, void* d_ws, size_t ws_size,
                              hipStream_t stream) {
    const int*   user_w  = (const int*)d_in[0];
    const int*   item_w  = (const int*)d_in[1];
    const int*   query_w = (const int*)d_in[2];
    const float* emb     = (const float*)d_in[3];
    const float* w_self  = (const float*)d_in[4];
    const float* b_self  = (const float*)d_in[5];
    const float* Wq      = (const float*)d_in[6];
    const float* bq      = (const float*)d_in[7];
    const float* w_red   = (const float*)d_in[8];
    const float* pf      = (const float*)d_in[9];

    float* ws       = (float*)d_ws;
    float* user_emb = ws;                          // 5120*128
    float* item_emb = user_emb + NDOC_UI * D;      // 5120*128
    float* q_emb    = item_emb + NDOC_UI * D;      // 256*128
    float* pv       = q_emb    + NB * D;           // 256*128
    float* evocab   = pv       + NB * D;           // 50000
    ushort* emb_bf  = (ushort*)(evocab + VOCAB);   // 4 quarter-tables, 12.8 MB
    float* out      = (float*)d_out;

    const size_t need_fast =
        (size_t)(2 * NDOC_UI * D + 2 * NB * D + VOCAB) * sizeof(float)
        + (size_t)VOCAB * D * sizeof(ushort);

    if (ws_size >= need_fast) {
        fused_kernel<<<GRID, TPB, 0, stream>>>(
            user_w, item_w, query_w, emb, w_self, b_self, Wq, bq, w_red, pf,
            user_emb, item_emb, q_emb, pv, evocab, emb_bf, out);
    } else {
        doc_embed_fp32_kernel<<<NDOC / 8, 256, 0, stream>>>(
            user_w, item_w, query_w, emb, w_self, b_self, user_emb, item_emb, q_emb);
        pv_kernel<<<dim3(128, 2), 256, 0, stream>>>(q_emb, Wq, bq, w_red, pv);
        attn_kernel<<<dim3(NB, 2), 256, 0, stream>>>(user_emb, item_emb, q_emb, pv, pf, out);
    }
}

// Round 3
// 148.147 us; speedup vs baseline: 3.6834x; 3.6834x over previous
//
#include <hip/hip_runtime.h>
#include <math.h>

#define D 128
#define H 64
#define W 100
#define R 20
#define NB 256
#define NDOC_UI (NB * R)   // 5120
#define NDOC    (2 * NDOC_UI + NB)   // 10496
#define VOCAB 50000

// e^(2x) identity tanh: exact saturation at +-1 via inf/0 in rcp.
__device__ __forceinline__ float fast_tanh(float x) {
    float u = __expf(2.0f * x);
    return 1.0f - 2.0f * __builtin_amdgcn_rcpf(1.0f + u);
}
__device__ __forceinline__ float fast_exp_tanh(float x) {
    return __expf(fast_tanh(x));
}

// fp32 -> bf16 round-to-nearest-even
__device__ __forceinline__ unsigned short f2bf(float f) {
    unsigned int b = __float_as_uint(f);
    b += 0x7fffu + ((b >> 16) & 1u);
    return (unsigned short)(b >> 16);
}

// ---------------- Kernel 0 (fast path): vocab prep ---------------------------
// e = exp(tanh(emb_row . w_self + b)) is doc-independent. Precompute per vocab
// row; store PRE-SCALED e*emb as bf16 in FOUR D-quarter tables (3.2 MB each,
// < 4 MiB per-XCD L2) so doc_embed can pin each quarter to an XCD pair.
__global__ __launch_bounds__(256) void vocab_prep_kernel(
    const float* __restrict__ emb, const float* __restrict__ w_self,
    const float* __restrict__ b_self,
    ushort* __restrict__ emb_bf, float* __restrict__ evocab)
{
    int tid = threadIdx.x, lane32 = tid & 31, grp = tid >> 5;
    int row = blockIdx.x * 8 + grp;            // 6250 blocks, exact
    float4 v   = ((const float4*)emb)[row * 32 + lane32];
    float4 ws4 = ((const float4*)w_self)[lane32];
    float p = v.x * ws4.x + v.y * ws4.y + v.z * ws4.z + v.w * ws4.w;
    p += __shfl_xor(p, 16, 64);
    p += __shfl_xor(p, 8, 64);
    p += __shfl_xor(p, 4, 64);
    p += __shfl_xor(p, 2, 64);
    p += __shfl_xor(p, 1, 64);
    float e = __expf(tanhf(p + b_self[0]));    // precise tanh: only 50K evals
    if (lane32 == 0) evocab[row] = e;
    ushort4 u;
    u.x = f2bf(v.x * e); u.y = f2bf(v.y * e);
    u.z = f2bf(v.z * e); u.w = f2bf(v.w * e);
    int q = lane32 >> 3;                       // d-quarter this lane belongs to
    ushort4* dst = (ushort4*)(emb_bf + (size_t)q * VOCAB * 32);
    dst[row * 8 + (lane32 & 7)] = u;
}

// ---------------- Kernel A (fast path): doc embed = weighted gather-sum ------
// One 32-lane group handles one (doc, d-quarter): 4 lanes x 16 B cover the
// 64 B quarter-row, 8 words per load-slot, 13 slots (last tail-masked).
// XCD pinning: blockIdx%8 ~ XCD; quarter = (B&7)>>1 -> per-XCD table
// footprint 3.2 MB < 4 MiB L2 -> table becomes L2-resident. Correctness does
// not depend on the mapping (each (doc,quarter) computed exactly once).
// R3 tweak: evocab gathers issued early, esum shuffle-reduce deferred to after
// the table-gather accumulation (inv only needed at the final write) -> the
// serial esum prefix (~4xL2 latency + 5 shuffles) hides under table gathers.
__global__ __launch_bounds__(128) void doc_embed_bf16_kernel(
    const int* __restrict__ user_w, const int* __restrict__ item_w,
    const int* __restrict__ query_w,
    const ushort* __restrict__ emb_bf, const float* __restrict__ evocab,
    float* __restrict__ user_emb, float* __restrict__ item_emb,
    float* __restrict__ q_emb)
{
    int tid    = threadIdx.x;
    int lane32 = tid & 31;
    int grp    = tid >> 5;                 // 0..3 (doc within block)
    unsigned B    = blockIdx.x;            // 10496 blocks = 1312 * 8
    unsigned quar = (B & 7) >> 1;          // 0..3 (XCD pair -> quarter)
    unsigned sub  = (B >> 3) * 2 + (B & 1);    // [0, 2624)
    int doc = (int)sub * 4 + grp;          // [0, 10496)

    const int* wp; float* outp;
    if (doc < NDOC_UI)        { wp = user_w + doc * W;               outp = user_emb + doc * D; }
    else if (doc < 2*NDOC_UI) { int t = doc - NDOC_UI;   wp = item_w  + t * W; outp = item_emb + t * D; }
    else                      { int t = doc - 2*NDOC_UI; wp = query_w + t * W; outp = q_emb    + t * D; }

    // Word ids: wreg[k] lane l holds words[k*32+l] (clamped dup for tail).
    int wreg[4];
    #pragma unroll
    for (int k = 0; k < 4; ++k) {
        int idx = k * 32 + lane32;
        wreg[k] = wp[idx > W - 1 ? W - 1 : idx];
    }

    // Issue the 4 evocab gathers NOW (VMEM pipe); reduce them later.
    float ev[4];
    #pragma unroll
    for (int k = 0; k < 4; ++k) ev[k] = evocab[wreg[k]];

    int permbase = (tid & 32) << 2;        // bpermute byte base of my 32-half
    int wsub     = lane32 >> 2;            // word within the 8-word slot (0..7)
    int sext     = lane32 & 3;             // 16 B slice of the 64 B quarter-row

    float acc[8];
    #pragma unroll
    for (int j = 0; j < 8; ++j) acc[j] = 0.f;

    const uint4* eq4 = (const uint4*)(emb_bf + (size_t)quar * VOCAB * 32);

    // 13 slots; slot s covers words 8s..8s+7 (section s>>2 is slot-uniform;
    // slot 12 covers 96..99 + clamped dups, masked via wsub<4).
    #pragma unroll
    for (int c = 0; c < 2; ++c) {
        const int n  = (c == 0) ? 7 : 6;
        const int s0 = (c == 0) ? 0 : 7;
        int wid[7]; uint4 v[7];
        for (int j = 0; j < n; ++j) {
            int s = s0 + j;
            wid[j] = __builtin_amdgcn_ds_bpermute(
                permbase | ((((8 * s) & 31) + wsub) << 2), wreg[s >> 2]);
        }
        for (int j = 0; j < n; ++j)
            v[j] = eq4[(size_t)(unsigned)wid[j] * 4 + sext];
        for (int j = 0; j < n; ++j) {
            if (s0 + j == 12 && wsub >= 4) break;   // tail mask (lane-static)
            uint4 x = v[j];
            acc[0] += __uint_as_float(x.x << 16);
            acc[1] += __uint_as_float(x.x & 0xffff0000u);
            acc[2] += __uint_as_float(x.y << 16);
            acc[3] += __uint_as_float(x.y & 0xffff0000u);
            acc[4] += __uint_as_float(x.z << 16);
            acc[5] += __uint_as_float(x.z & 0xffff0000u);
            acc[6] += __uint_as_float(x.w << 16);
            acc[7] += __uint_as_float(x.w & 0xffff0000u);
        }
    }

    // Deferred esum reduce: tail-masked lanes (wreg[3] dups) only count lane<4.
    float ep = ev[0] + ev[1] + ev[2] + (lane32 < 4 ? ev[3] : 0.f);
    ep += __shfl_xor(ep, 16, 64);
    ep += __shfl_xor(ep, 8, 64);
    ep += __shfl_xor(ep, 4, 64);
    ep += __shfl_xor(ep, 2, 64);
    ep += __shfl_xor(ep, 1, 64);
    float inv = 1.f / ep;

    // Reduce over the 8 word-subgroups (xor 4, 8, 16 within the 32-lane group).
    #pragma unroll
    for (int j = 0; j < 8; ++j) {
        acc[j] += __shfl_xor(acc[j], 4, 64);
        acc[j] += __shfl_xor(acc[j], 8, 64);
        acc[j] += __shfl_xor(acc[j], 16, 64);
    }

    if (wsub == 0) {   // lanes 0..3 hold dims quar*32 + sext*8 .. +7
        float* o = outp + quar * 32 + sext * 8;
        *(float4*)o       = make_float4(acc[0]*inv, acc[1]*inv, acc[2]*inv, acc[3]*inv);
        *(float4*)(o + 4) = make_float4(acc[4]*inv, acc[5]*inv, acc[6]*inv, acc[7]*inv);
    }
}

// ---------------- Kernel A' (fallback, R4-proven): fp32 gather doc embed -----
__global__ __launch_bounds__(256, 7) void doc_embed_fp32_kernel(
    const int* __restrict__ user_w, const int* __restrict__ item_w,
    const int* __restrict__ query_w,
    const float* __restrict__ emb, const float* __restrict__ w_self,
    const float* __restrict__ b_self,
    float* __restrict__ user_emb, float* __restrict__ item_emb,
    float* __restrict__ q_emb)
{
    int tid    = threadIdx.x;
    int lane32 = tid & 31;
    int grp    = tid >> 5;
    int doc    = blockIdx.x * 8 + grp;

    const int* wp; float* outp;
    if (doc < NDOC_UI)        { wp = user_w + doc * W;               outp = user_emb + doc * D; }
    else if (doc < 2*NDOC_UI) { int t = doc - NDOC_UI;   wp = item_w  + t * W; outp = item_emb + t * D; }
    else                      { int t = doc - 2*NDOC_UI; wp = query_w + t * W; outp = q_emb    + t * D; }

    int wreg[4];
    #pragma unroll
    for (int k = 0; k < 4; ++k) {
        int idx = k * 32 + lane32;
        wreg[k] = wp[idx > W - 1 ? W - 1 : idx];
    }

    float4 ws4 = ((const float4*)w_self)[lane32];
    float  bs  = b_self[0];
    const float4* emb4 = (const float4*)emb;
    int permbase = (tid & 32) * 4;

    float4 acc  = make_float4(0.f, 0.f, 0.f, 0.f);
    float  esum = 0.f;

    #pragma unroll
    for (int c = 0; c < 10; ++c) {
        int word[10];
        #pragma unroll
        for (int j = 0; j < 10; ++j) {
            int w = c * 10 + j;
            word[j] = __builtin_amdgcn_ds_bpermute(permbase | ((w & 31) * 4),
                                                   wreg[w >> 5]);
        }
        float4 v[10];
        #pragma unroll
        for (int j = 0; j < 10; ++j)
            v[j] = emb4[(size_t)word[j] * 32 + lane32];

        #pragma unroll
        for (int j = 0; j < 10; ++j) {
            float p = v[j].x * ws4.x + v[j].y * ws4.y + v[j].z * ws4.z + v[j].w * ws4.w;
            p += __shfl_xor(p, 16, 64);
            p += __shfl_xor(p, 8, 64);
            p += __shfl_xor(p, 4, 64);
            p += __shfl_xor(p, 2, 64);
            p += __shfl_xor(p, 1, 64);
            float e = fast_exp_tanh(p + bs);
            esum += e;
            acc.x += e * v[j].x;
            acc.y += e * v[j].y;
            acc.z += e * v[j].z;
            acc.w += e * v[j].w;
        }
    }

    float inv = 1.0f / esum;
    acc.x *= inv; acc.y *= inv; acc.z *= inv; acc.w *= inv;
    ((float4*)outp)[lane32] = acc;
}

// ---------------- Kernel B: pv[b,d] = sum_h tanh(q@Wq+bq)[b,d*64+h]*w_red[h] -
// Per-thread tile 8m x 4n; q rows direct from global (L2-resident, broadcast),
// double-buffered k4 prefetch; only Wq staged in LDS.
__global__ __launch_bounds__(256) void pv_kernel(
    const float* __restrict__ q_emb, const float* __restrict__ Wq,
    const float* __restrict__ bq, const float* __restrict__ w_red,
    float* __restrict__ pv)
{
    __shared__ __align__(16) float Wb[128 * 68];    // 34.8 KB

    int dd  = blockIdx.x;          // 0..127
    int m0g = blockIdx.y * 128;    // row offset (0 or 128)
    int tid = threadIdx.x;

    {
        int rrow = tid >> 4;
        int f4   = tid & 15;
        #pragma unroll
        for (int pass = 0; pass < 8; ++pass) {
            int k = pass * 16 + rrow;
            float4 vw = ((const float4*)Wq)[k * 2048 + dd * 16 + f4];
            *(float4*)&Wb[k * 68 + f4 * 4] = vw;
        }
    }
    __syncthreads();

    int nthr = tid & 15;
    int mthr = tid >> 4;
    int n0 = nthr * 4;
    const float4* q4 = (const float4*)q_emb;
    int mbase = (m0g + mthr * 8) * 32;

    float acc[8][4];
    #pragma unroll
    for (int i = 0; i < 8; ++i)
        #pragma unroll
        for (int j = 0; j < 4; ++j) acc[i][j] = 0.f;

    float4 qa[8], qb[8];
    #pragma unroll
    for (int i = 0; i < 8; ++i) qa[i] = q4[mbase + i * 32];

    for (int k4 = 0; k4 < 32; ++k4) {
        if (k4 < 31) {
            #pragma unroll
            for (int i = 0; i < 8; ++i) qb[i] = q4[mbase + i * 32 + k4 + 1];
        }
        #pragma unroll
        for (int kk = 0; kk < 4; ++kk) {
            float4 wv = *(const float4*)&Wb[(k4 * 4 + kk) * 68 + n0];
            #pragma unroll
            for (int i = 0; i < 8; ++i) {
                float a = (kk == 0) ? qa[i].x : (kk == 1) ? qa[i].y
                        : (kk == 2) ? qa[i].z : qa[i].w;
                acc[i][0] += a * wv.x;
                acc[i][1] += a * wv.y;
                acc[i][2] += a * wv.z;
                acc[i][3] += a * wv.w;
            }
        }
        #pragma unroll
        for (int i = 0; i < 8; ++i) qa[i] = qb[i];
    }

    float4 bqv = ((const float4*)bq)[dd * 16 + nthr];
    float4 wrv = ((const float4*)w_red)[nthr];

    #pragma unroll
    for (int i = 0; i < 8; ++i) {
        float s = fast_tanh(acc[i][0] + bqv.x) * wrv.x
                + fast_tanh(acc[i][1] + bqv.y) * wrv.y
                + fast_tanh(acc[i][2] + bqv.z) * wrv.z
                + fast_tanh(acc[i][3] + bqv.w) * wrv.w;
        s += __shfl_xor(s, 1, 64);
        s += __shfl_xor(s, 2, 64);
        s += __shfl_xor(s, 4, 64);
        s += __shfl_xor(s, 8, 64);
        if (nthr == 0) pv[(m0g + mthr * 8 + i) * 128 + dd] = s;
    }
}

// ---------------- Kernel C: review attention + output ------------------------
__global__ __launch_bounds__(256) void attn_kernel(
    const float* __restrict__ user_emb, const float* __restrict__ item_emb,
    const float* __restrict__ q_emb, const float* __restrict__ pv,
    const float* __restrict__ pf, float* __restrict__ out)
{
    __shared__ float rev[R * 129];
    __shared__ float pvl[D];
    __shared__ float sc[R];

    int b   = blockIdx.x;
    int set = blockIdx.y;
    const float* revg = (set == 0 ? user_emb : item_emb) + b * R * D;
    int tid = threadIdx.x;

    for (int idx = tid; idx < R * D; idx += 256)
        rev[(idx >> 7) * 129 + (idx & 127)] = revg[idx];
    if (tid < D) pvl[tid] = pv[b * D + tid];
    __syncthreads();

    if (tid < R) {
        float s = 0.f;
        const float* row = &rev[tid * 129];
        #pragma unroll 16
        for (int k = 0; k < D; ++k) s += row[k] * pvl[k];
        sc[tid] = s;
    }
    __syncthreads();

    float m = -1e30f;
    for (int r = 0; r < R; ++r) m = fmaxf(m, sc[r]);
    float sum = 0.f;
    for (int r = 0; r < R; ++r) sum += __expf(sc[r] - m);
    float inv = 1.f / sum;

    if (tid < D) {
        float acc = 0.f;
        for (int r = 0; r < R; ++r)
            acc += __expf(sc[r] - m) * inv * rev[r * 129 + tid];
        if (set == 0) {
            acc += pf[0] * q_emb[b * D + tid];
            out[b * D + tid] = acc;
        } else {
            out[NB * D + b * D + tid] = acc;
        }
    }
}

extern "C" void kernel_launch(void* const* d_in, const int* in_sizes, int n_in,
                              void* d_out, int out_size, void* d_ws, size_t ws_size,
                              hipStream_t stream) {
    const int*   user_w  = (const int*)d_in[0];
    const int*   item_w  = (const int*)d_in[1];
    const int*   query_w = (const int*)d_in[2];
    const float* emb     = (const float*)d_in[3];
    const float* w_self  = (const float*)d_in[4];
    const float* b_self  = (const float*)d_in[5];
    const float* Wq      = (const float*)d_in[6];
    const float* bq      = (const float*)d_in[7];
    const float* w_red   = (const float*)d_in[8];
    const float* pf      = (const float*)d_in[9];

    float* ws       = (float*)d_ws;
    float* user_emb = ws;                          // 5120*128
    float* item_emb = user_emb + NDOC_UI * D;      // 5120*128
    float* q_emb    = item_emb + NDOC_UI * D;      // 256*128
    float* pv       = q_emb    + NB * D;           // 256*128
    float* evocab   = pv       + NB * D;           // 50000
    ushort* emb_bf  = (ushort*)(evocab + VOCAB);   // 4 quarter-tables, 12.8 MB
    float* out      = (float*)d_out;

    // Fast path needs the bf16 vocab table in ws; guard against small ws.
    const size_t need_fast =
        (size_t)(2 * NDOC_UI * D + 2 * NB * D + VOCAB) * sizeof(float)
        + (size_t)VOCAB * D * sizeof(ushort);      // 18,505,024 B

    if (ws_size >= need_fast) {
        vocab_prep_kernel<<<VOCAB / 8, 256, 0, stream>>>(
            emb, w_self, b_self, emb_bf, evocab);
        doc_embed_bf16_kernel<<<NDOC, 128, 0, stream>>>(
            user_w, item_w, query_w, emb_bf, evocab, user_emb, item_emb, q_emb);
    } else {
        doc_embed_fp32_kernel<<<NDOC / 8, 256, 0, stream>>>(
            user_w, item_w, query_w, emb, w_self, b_self, user_emb, item_emb, q_emb);
    }
    pv_kernel<<<dim3(128, 2), 256, 0, stream>>>(q_emb, Wq, bq, w_red, pv);
    attn_kernel<<<dim3(NB, 2), 256, 0, stream>>>(user_emb, item_emb, q_emb, pv, pf, out);
}

// Round 4
// 147.516 us; speedup vs baseline: 3.6991x; 1.0043x over previous
//
#include <hip/hip_runtime.h>
#include <math.h>

#define D 128
#define H 64
#define W 100
#define R 20
#define NB 256
#define NDOC_UI (NB * R)   // 5120
#define NDOC    (2 * NDOC_UI + NB)   // 10496
#define VOCAB 50000

// e^(2x) identity tanh: exact saturation at +-1 via inf/0 in rcp.
__device__ __forceinline__ float fast_tanh(float x) {
    float u = __expf(2.0f * x);
    return 1.0f - 2.0f * __builtin_amdgcn_rcpf(1.0f + u);
}
__device__ __forceinline__ float fast_exp_tanh(float x) {
    return __expf(fast_tanh(x));
}

// fp32 -> bf16 round-to-nearest-even
__device__ __forceinline__ unsigned short f2bf(float f) {
    unsigned int b = __float_as_uint(f);
    b += 0x7fffu + ((b >> 16) & 1u);
    return (unsigned short)(b >> 16);
}

// ---------------- Kernel 0 (fast path): vocab prep ---------------------------
// e = exp(tanh(emb_row . w_self + b)) is doc-independent. Precompute per vocab
// row; store PRE-SCALED e*emb as bf16 in FOUR D-quarter tables (3.2 MB each,
// < 4 MiB per-XCD L2) so doc_embed can pin each quarter to an XCD pair.
__global__ __launch_bounds__(256) void vocab_prep_kernel(
    const float* __restrict__ emb, const float* __restrict__ w_self,
    const float* __restrict__ b_self,
    ushort* __restrict__ emb_bf, float* __restrict__ evocab)
{
    int tid = threadIdx.x, lane32 = tid & 31, grp = tid >> 5;
    int row = blockIdx.x * 8 + grp;            // 6250 blocks, exact
    float4 v   = ((const float4*)emb)[row * 32 + lane32];
    float4 ws4 = ((const float4*)w_self)[lane32];
    float p = v.x * ws4.x + v.y * ws4.y + v.z * ws4.z + v.w * ws4.w;
    p += __shfl_xor(p, 16, 64);
    p += __shfl_xor(p, 8, 64);
    p += __shfl_xor(p, 4, 64);
    p += __shfl_xor(p, 2, 64);
    p += __shfl_xor(p, 1, 64);
    float e = __expf(tanhf(p + b_self[0]));    // precise tanh: only 50K evals
    if (lane32 == 0) evocab[row] = e;
    ushort4 u;
    u.x = f2bf(v.x * e); u.y = f2bf(v.y * e);
    u.z = f2bf(v.z * e); u.w = f2bf(v.w * e);
    int q = lane32 >> 3;                       // d-quarter this lane belongs to
    ushort4* dst = (ushort4*)(emb_bf + (size_t)q * VOCAB * 32);
    dst[row * 8 + (lane32 & 7)] = u;
}

// ---------------- Kernel A (fast path): doc embed = weighted gather-sum ------
// One 32-lane group handles one (doc, d-quarter): 4 lanes x 16 B cover the
// 64 B quarter-row, 8 words per load-slot, 13 slots (last tail-masked).
// XCD pinning: blockIdx%8 ~ XCD; quarter = (B&7)>>1 -> per-XCD table
// footprint 3.2 MB < 4 MiB L2 -> table becomes L2-resident. (R0-champion form.)
__global__ __launch_bounds__(128) void doc_embed_bf16_kernel(
    const int* __restrict__ user_w, const int* __restrict__ item_w,
    const int* __restrict__ query_w,
    const ushort* __restrict__ emb_bf, const float* __restrict__ evocab,
    float* __restrict__ user_emb, float* __restrict__ item_emb,
    float* __restrict__ q_emb)
{
    int tid    = threadIdx.x;
    int lane32 = tid & 31;
    int grp    = tid >> 5;                 // 0..3 (doc within block)
    unsigned B    = blockIdx.x;            // 10496 blocks = 1312 * 8
    unsigned quar = (B & 7) >> 1;          // 0..3 (XCD pair -> quarter)
    unsigned sub  = (B >> 3) * 2 + (B & 1);    // [0, 2624)
    int doc = (int)sub * 4 + grp;          // [0, 10496)

    const int* wp; float* outp;
    if (doc < NDOC_UI)        { wp = user_w + doc * W;               outp = user_emb + doc * D; }
    else if (doc < 2*NDOC_UI) { int t = doc - NDOC_UI;   wp = item_w  + t * W; outp = item_emb + t * D; }
    else                      { int t = doc - 2*NDOC_UI; wp = query_w + t * W; outp = q_emb    + t * D; }

    // Word ids: wreg[k] lane l holds words[k*32+l] (clamped dup for tail).
    int wreg[4];
    #pragma unroll
    for (int k = 0; k < 4; ++k) {
        int idx = k * 32 + lane32;
        wreg[k] = wp[idx > W - 1 ? W - 1 : idx];
    }

    // esum: gather evocab (200 KB, cache-resident), mask tail, 5-shuffle reduce.
    float ep = 0.f;
    #pragma unroll
    for (int k = 0; k < 4; ++k) {
        float e = evocab[wreg[k]];
        if (k < 3 || lane32 < 4) ep += e;
    }
    ep += __shfl_xor(ep, 16, 64);
    ep += __shfl_xor(ep, 8, 64);
    ep += __shfl_xor(ep, 4, 64);
    ep += __shfl_xor(ep, 2, 64);
    ep += __shfl_xor(ep, 1, 64);
    float inv = 1.f / ep;

    int permbase = (tid & 32) << 2;        // bpermute byte base of my 32-half
    int wsub     = lane32 >> 2;            // word within the 8-word slot (0..7)
    int sext     = lane32 & 3;             // 16 B slice of the 64 B quarter-row

    float acc[8];
    #pragma unroll
    for (int j = 0; j < 8; ++j) acc[j] = 0.f;

    const uint4* eq4 = (const uint4*)(emb_bf + (size_t)quar * VOCAB * 32);

    // 13 slots; slot s covers words 8s..8s+7 (section s>>2 is slot-uniform;
    // slot 12 covers 96..99 + clamped dups, masked via wsub<4).
    #pragma unroll
    for (int c = 0; c < 2; ++c) {
        const int n  = (c == 0) ? 7 : 6;
        const int s0 = (c == 0) ? 0 : 7;
        int wid[7]; uint4 v[7];
        for (int j = 0; j < n; ++j) {
            int s = s0 + j;
            wid[j] = __builtin_amdgcn_ds_bpermute(
                permbase | ((((8 * s) & 31) + wsub) << 2), wreg[s >> 2]);
        }
        for (int j = 0; j < n; ++j)
            v[j] = eq4[(size_t)(unsigned)wid[j] * 4 + sext];
        for (int j = 0; j < n; ++j) {
            if (s0 + j == 12 && wsub >= 4) break;   // tail mask (lane-static)
            uint4 x = v[j];
            acc[0] += __uint_as_float(x.x << 16);
            acc[1] += __uint_as_float(x.x & 0xffff0000u);
            acc[2] += __uint_as_float(x.y << 16);
            acc[3] += __uint_as_float(x.y & 0xffff0000u);
            acc[4] += __uint_as_float(x.z << 16);
            acc[5] += __uint_as_float(x.z & 0xffff0000u);
            acc[6] += __uint_as_float(x.w << 16);
            acc[7] += __uint_as_float(x.w & 0xffff0000u);
        }
    }

    // Reduce over the 8 word-subgroups (xor 4, 8, 16 within the 32-lane group).
    #pragma unroll
    for (int j = 0; j < 8; ++j) {
        acc[j] += __shfl_xor(acc[j], 4, 64);
        acc[j] += __shfl_xor(acc[j], 8, 64);
        acc[j] += __shfl_xor(acc[j], 16, 64);
    }

    if (wsub == 0) {   // lanes 0..3 hold dims quar*32 + sext*8 .. +7
        float* o = outp + quar * 32 + sext * 8;
        *(float4*)o       = make_float4(acc[0]*inv, acc[1]*inv, acc[2]*inv, acc[3]*inv);
        *(float4*)(o + 4) = make_float4(acc[4]*inv, acc[5]*inv, acc[6]*inv, acc[7]*inv);
    }
}

// ---------------- Kernel A' (fallback, R4-proven): fp32 gather doc embed -----
__global__ __launch_bounds__(256, 7) void doc_embed_fp32_kernel(
    const int* __restrict__ user_w, const int* __restrict__ item_w,
    const int* __restrict__ query_w,
    const float* __restrict__ emb, const float* __restrict__ w_self,
    const float* __restrict__ b_self,
    float* __restrict__ user_emb, float* __restrict__ item_emb,
    float* __restrict__ q_emb)
{
    int tid    = threadIdx.x;
    int lane32 = tid & 31;
    int grp    = tid >> 5;
    int doc    = blockIdx.x * 8 + grp;

    const int* wp; float* outp;
    if (doc < NDOC_UI)        { wp = user_w + doc * W;               outp = user_emb + doc * D; }
    else if (doc < 2*NDOC_UI) { int t = doc - NDOC_UI;   wp = item_w  + t * W; outp = item_emb + t * D; }
    else                      { int t = doc - 2*NDOC_UI; wp = query_w + t * W; outp = q_emb    + t * D; }

    int wreg[4];
    #pragma unroll
    for (int k = 0; k < 4; ++k) {
        int idx = k * 32 + lane32;
        wreg[k] = wp[idx > W - 1 ? W - 1 : idx];
    }

    float4 ws4 = ((const float4*)w_self)[lane32];
    float  bs  = b_self[0];
    const float4* emb4 = (const float4*)emb;
    int permbase = (tid & 32) * 4;

    float4 acc  = make_float4(0.f, 0.f, 0.f, 0.f);
    float  esum = 0.f;

    #pragma unroll
    for (int c = 0; c < 10; ++c) {
        int word[10];
        #pragma unroll
        for (int j = 0; j < 10; ++j) {
            int w = c * 10 + j;
            word[j] = __builtin_amdgcn_ds_bpermute(permbase | ((w & 31) * 4),
                                                   wreg[w >> 5]);
        }
        float4 v[10];
        #pragma unroll
        for (int j = 0; j < 10; ++j)
            v[j] = emb4[(size_t)word[j] * 32 + lane32];

        #pragma unroll
        for (int j = 0; j < 10; ++j) {
            float p = v[j].x * ws4.x + v[j].y * ws4.y + v[j].z * ws4.z + v[j].w * ws4.w;
            p += __shfl_xor(p, 16, 64);
            p += __shfl_xor(p, 8, 64);
            p += __shfl_xor(p, 4, 64);
            p += __shfl_xor(p, 2, 64);
            p += __shfl_xor(p, 1, 64);
            float e = fast_exp_tanh(p + bs);
            esum += e;
            acc.x += e * v[j].x;
            acc.y += e * v[j].y;
            acc.z += e * v[j].z;
            acc.w += e * v[j].w;
        }
    }

    float inv = 1.0f / esum;
    acc.x *= inv; acc.y *= inv; acc.z *= inv; acc.w *= inv;
    ((float4*)outp)[lane32] = acc;
}

// ---------------- Kernel B: pv[b,d] = sum_h tanh(q@Wq+bq)[b,d*64+h]*w_red[h] -
// R4: 512 threads (2 waves/SIMD instead of 1) to hide the ds_read->FMA latency
// chain; per-thread tile 4m x 4n (was 8x4). Same grid, same Wq traffic, same
// per-output accumulation order.
__global__ __launch_bounds__(512) void pv_kernel(
    const float* __restrict__ q_emb, const float* __restrict__ Wq,
    const float* __restrict__ bq, const float* __restrict__ w_red,
    float* __restrict__ pv)
{
    __shared__ __align__(16) float Wb[128 * 68];    // 34.8 KB

    int dd  = blockIdx.x;          // 0..127
    int m0g = blockIdx.y * 128;    // row offset (0 or 128)
    int tid = threadIdx.x;

    {
        int rrow = tid >> 4;                  // 0..31
        int f4   = tid & 15;
        #pragma unroll
        for (int pass = 0; pass < 4; ++pass) {
            int k = pass * 32 + rrow;
            float4 vw = ((const float4*)Wq)[k * 2048 + dd * 16 + f4];
            *(float4*)&Wb[k * 68 + f4 * 4] = vw;
        }
    }
    __syncthreads();

    int nthr = tid & 15;
    int mthr = tid >> 4;                      // 0..31
    int n0 = nthr * 4;
    const float4* q4 = (const float4*)q_emb;
    int mrow = m0g + mthr * 4;

    float acc[4][4];
    #pragma unroll
    for (int i = 0; i < 4; ++i)
        #pragma unroll
        for (int j = 0; j < 4; ++j) acc[i][j] = 0.f;

    float4 qa[4], qb[4];
    #pragma unroll
    for (int i = 0; i < 4; ++i) qa[i] = q4[(mrow + i) * 32];

    for (int k4 = 0; k4 < 32; ++k4) {
        if (k4 < 31) {
            #pragma unroll
            for (int i = 0; i < 4; ++i) qb[i] = q4[(mrow + i) * 32 + k4 + 1];
        }
        #pragma unroll
        for (int kk = 0; kk < 4; ++kk) {
            float4 wv = *(const float4*)&Wb[(k4 * 4 + kk) * 68 + n0];
            #pragma unroll
            for (int i = 0; i < 4; ++i) {
                float a = (kk == 0) ? qa[i].x : (kk == 1) ? qa[i].y
                        : (kk == 2) ? qa[i].z : qa[i].w;
                acc[i][0] += a * wv.x;
                acc[i][1] += a * wv.y;
                acc[i][2] += a * wv.z;
                acc[i][3] += a * wv.w;
            }
        }
        #pragma unroll
        for (int i = 0; i < 4; ++i) qa[i] = qb[i];
    }

    float4 bqv = ((const float4*)bq)[dd * 16 + nthr];
    float4 wrv = ((const float4*)w_red)[nthr];

    #pragma unroll
    for (int i = 0; i < 4; ++i) {
        float s = fast_tanh(acc[i][0] + bqv.x) * wrv.x
                + fast_tanh(acc[i][1] + bqv.y) * wrv.y
                + fast_tanh(acc[i][2] + bqv.z) * wrv.z
                + fast_tanh(acc[i][3] + bqv.w) * wrv.w;
        s += __shfl_xor(s, 1, 64);
        s += __shfl_xor(s, 2, 64);
        s += __shfl_xor(s, 4, 64);
        s += __shfl_xor(s, 8, 64);
        if (nthr == 0) pv[(mrow + i) * 128 + dd] = s;
    }
}

// ---------------- Kernel C: review attention + output ------------------------
// R4: score dots wave-parallel (8 lanes per review row, shfl-reduce) instead
// of 20 serial 128-iter loops on 20 threads; softmax exps computed once into
// LDS (20 per block, was ~5000). Row stride 132 keeps strided reads <=2-way.
__global__ __launch_bounds__(256) void attn_kernel(
    const float* __restrict__ user_emb, const float* __restrict__ item_emb,
    const float* __restrict__ q_emb, const float* __restrict__ pv,
    const float* __restrict__ pf, float* __restrict__ out)
{
    __shared__ float rev[R * 132];
    __shared__ float pvl[D];
    __shared__ float sc[R];
    __shared__ float ew[R];

    int b   = blockIdx.x;
    int set = blockIdx.y;
    const float* revg = (set == 0 ? user_emb : item_emb) + b * R * D;
    int tid = threadIdx.x;

    for (int idx = tid; idx < R * D; idx += 256)
        rev[(idx >> 7) * 132 + (idx & 127)] = revg[idx];
    if (tid < D) pvl[tid] = pv[b * D + tid];
    __syncthreads();

    if (tid < R * 8) {                        // 160 threads: 8 lanes per row
        int r   = tid >> 3;
        int sub = tid & 7;
        const float* row = &rev[r * 132];
        float s = 0.f;
        #pragma unroll
        for (int j = 0; j < 16; ++j) {
            int k = sub + j * 8;
            s += row[k] * pvl[k];
        }
        s += __shfl_xor(s, 1, 64);
        s += __shfl_xor(s, 2, 64);
        s += __shfl_xor(s, 4, 64);
        if (sub == 0) sc[r] = s;
    }
    __syncthreads();

    float m = -1e30f;
    #pragma unroll
    for (int r = 0; r < R; ++r) m = fmaxf(m, sc[r]);
    if (tid < R) ew[tid] = __expf(sc[tid] - m);
    __syncthreads();

    float sum = 0.f;
    #pragma unroll
    for (int r = 0; r < R; ++r) sum += ew[r];
    float inv = 1.f / sum;

    if (tid < D) {
        float acc = 0.f;
        #pragma unroll
        for (int r = 0; r < R; ++r)
            acc += ew[r] * rev[r * 132 + tid];
        acc *= inv;
        if (set == 0) {
            acc += pf[0] * q_emb[b * D + tid];
            out[b * D + tid] = acc;
        } else {
            out[NB * D + b * D + tid] = acc;
        }
    }
}

extern "C" void kernel_launch(void* const* d_in, const int* in_sizes, int n_in,
                              void* d_out, int out_size, void* d_ws, size_t ws_size,
                              hipStream_t stream) {
    const int*   user_w  = (const int*)d_in[0];
    const int*   item_w  = (const int*)d_in[1];
    const int*   query_w = (const int*)d_in[2];
    const float* emb     = (const float*)d_in[3];
    const float* w_self  = (const float*)d_in[4];
    const float* b_self  = (const float*)d_in[5];
    const float* Wq      = (const float*)d_in[6];
    const float* bq      = (const float*)d_in[7];
    const float* w_red   = (const float*)d_in[8];
    const float* pf      = (const float*)d_in[9];

    float* ws       = (float*)d_ws;
    float* user_emb = ws;                          // 5120*128
    float* item_emb = user_emb + NDOC_UI * D;      // 5120*128
    float* q_emb    = item_emb + NDOC_UI * D;      // 256*128
    float* pv       = q_emb    + NB * D;           // 256*128
    float* evocab   = pv       + NB * D;           // 50000
    ushort* emb_bf  = (ushort*)(evocab + VOCAB);   // 4 quarter-tables, 12.8 MB
    float* out      = (float*)d_out;

    // Fast path needs the bf16 vocab table in ws; guard against small ws.
    const size_t need_fast =
        (size_t)(2 * NDOC_UI * D + 2 * NB * D + VOCAB) * sizeof(float)
        + (size_t)VOCAB * D * sizeof(ushort);      // 18,505,024 B

    if (ws_size >= need_fast) {
        vocab_prep_kernel<<<VOCAB / 8, 256, 0, stream>>>(
            emb, w_self, b_self, emb_bf, evocab);
        doc_embed_bf16_kernel<<<NDOC, 128, 0, stream>>>(
            user_w, item_w, query_w, emb_bf, evocab, user_emb, item_emb, q_emb);
    } else {
        doc_embed_fp32_kernel<<<NDOC / 8, 256, 0, stream>>>(
            user_w, item_w, query_w, emb, w_self, b_self, user_emb, item_emb, q_emb);
    }
    pv_kernel<<<dim3(128, 2), 512, 0, stream>>>(q_emb, Wq, bq, w_red, pv);
    attn_kernel<<<dim3(NB, 2), 256, 0, stream>>>(user_emb, item_emb, q_emb, pv, pf, out);
}